// Round 1
// baseline (667.161 us; speedup 1.0000x reference)
//
#include <hip/hip_runtime.h>
#include <hip/hip_bf16.h>
#include <math.h>

#define NUM_GRAPHS 1024

typedef __attribute__((ext_vector_type(8))) short bf16x8;
typedef __attribute__((ext_vector_type(4))) float f32x4;

static __device__ __forceinline__ unsigned short f2bf(float f) {
    union { float f; unsigned u; } v; v.f = f;
    unsigned r = v.u + 0x7fffu + ((v.u >> 16) & 1u);   // round-to-nearest-even
    return (unsigned short)(r >> 16);
}

// ---------------- CSR build ----------------
__global__ void k_deg(const int* __restrict__ dstI, int E, int* __restrict__ deg) {
    int e = blockIdx.x * 256 + threadIdx.x;
    if (e < E) atomicAdd(&deg[dstI[e]], 1);
}

__global__ void k_scan1(const int* __restrict__ deg, int N,
                        int* __restrict__ excl, int* __restrict__ bsum) {
    __shared__ int s[256];
    int i = blockIdx.x * 256 + threadIdx.x;
    int v = (i < N) ? deg[i] : 0;
    s[threadIdx.x] = v;
    __syncthreads();
    for (int off = 1; off < 256; off <<= 1) {
        int t = (threadIdx.x >= off) ? s[threadIdx.x - off] : 0;
        __syncthreads();
        s[threadIdx.x] += t;
        __syncthreads();
    }
    if (i < N) excl[i] = s[threadIdx.x] - v;
    if (threadIdx.x == 255) bsum[blockIdx.x] = s[255];
}

__global__ void k_scan2(int* __restrict__ bsum, int nb) {
    __shared__ int s[1024];
    int t = threadIdx.x;
    int v = (t < nb) ? bsum[t] : 0;
    s[t] = v;
    __syncthreads();
    for (int off = 1; off < 1024; off <<= 1) {
        int u = (t >= off) ? s[t - off] : 0;
        __syncthreads();
        s[t] += u;
        __syncthreads();
    }
    if (t < nb) bsum[t] = s[t] - v;   // exclusive block offsets
}

__global__ void k_scan3(const int* __restrict__ excl, const int* __restrict__ bsum,
                        int N, int E, int* __restrict__ rp, int* __restrict__ cursor) {
    int i = blockIdx.x * 256 + threadIdx.x;
    if (i < N) {
        int v = excl[i] + bsum[i >> 8];
        rp[i] = v;
        cursor[i] = v;
    }
    if (i == 0) rp[N] = E;
}

__global__ void k_fill(const int* __restrict__ ei, int E,
                       int* __restrict__ cursor, int* __restrict__ srcs) {
    int e = blockIdx.x * 256 + threadIdx.x;
    if (e < E) {
        int s = ei[e];
        int d = ei[(size_t)E + e];
        int p = atomicAdd(&cursor[d], 1);
        srcs[p] = s;
    }
}

// ---------------- aggregation: out[n] = H[n] + sum_{e: dst=n} H[src_e] ----------------
__global__ void k_agg(const float* __restrict__ H, const int* __restrict__ rp,
                      const int* __restrict__ srcs, int N, float* __restrict__ out) {
    int wid = (blockIdx.x * blockDim.x + threadIdx.x) >> 6;
    int lane = threadIdx.x & 63;
    if (wid >= N) return;
    int beg = rp[wid], end = rp[wid + 1];
    const size_t fo = (size_t)lane * 2;
    float2 acc = *(const float2*)&H[(size_t)wid * 128 + fo];
    int j = beg;
    for (; j + 4 <= end; j += 4) {
        int s0 = srcs[j], s1 = srcs[j + 1], s2 = srcs[j + 2], s3 = srcs[j + 3];
        float2 v0 = *(const float2*)&H[(size_t)s0 * 128 + fo];
        float2 v1 = *(const float2*)&H[(size_t)s1 * 128 + fo];
        float2 v2 = *(const float2*)&H[(size_t)s2 * 128 + fo];
        float2 v3 = *(const float2*)&H[(size_t)s3 * 128 + fo];
        acc.x += v0.x + v1.x + v2.x + v3.x;
        acc.y += v0.y + v1.y + v2.y + v3.y;
    }
    for (; j < end; ++j) {
        int s = srcs[j];
        float2 v = *(const float2*)&H[(size_t)s * 128 + fo];
        acc.x += v.x; acc.y += v.y;
    }
    *(float2*)&out[(size_t)wid * 128 + fo] = acc;
}

// ---------------- weight prep: fp32 W[k][n] -> bf16 W^T[n][k] (packed, stride 128) ----------------
__global__ void k_prepw(const float* __restrict__ W, unsigned short* __restrict__ WT) {
    int idx = blockIdx.x * 256 + threadIdx.x;   // 0..16383
    int k = idx >> 7, n = idx & 127;
    WT[n * 128 + k] = f2bf(W[idx]);
}

// ---------------- fused 2-layer MLP: Y = relu(relu(U@Wa+ba)@Wb+bb) ----------------
// XOR-chunk swizzle: logical (row, elem k) -> row*128 + ((k/8 ^ (row&7))*8 + k%8
__device__ __forceinline__ int swz_base(int row, int chunk) {
    return row * 128 + ((chunk ^ (row & 7)) << 3);
}

__global__ __launch_bounds__(256, 2)
void k_mlp(const float* __restrict__ U, int N,
           const unsigned short* __restrict__ WaT, const float* __restrict__ ba,
           const unsigned short* __restrict__ WbT, const float* __restrict__ bb,
           float* __restrict__ Y) {
    __shared__ unsigned short lA[128 * 128];   // 32 KB: A tile, then T tile
    __shared__ unsigned short lW[128 * 128];   // 32 KB: Wa^T, then Wb^T

    const int tid = threadIdx.x;
    const int lane = tid & 63;
    const int w = tid >> 6;              // wave 0..3
    const int wr = (w >> 1) * 64;        // wave row offset
    const int wc = (w & 1) * 64;         // wave col offset
    const int r0 = blockIdx.x * 128;

    // ---- stage A: fp32 global -> bf16 LDS (swizzled) ----
    {
        const float4* U4 = (const float4*)U;
        #pragma unroll
        for (int i = 0; i < 16; ++i) {
            int c = tid + 256 * i;              // 0..4095
            int row = c >> 5, q = c & 31;       // q: float4 index in row (8B half-chunk)
            float4 v = (r0 + row < N) ? U4[(size_t)(r0 + row) * 32 + q]
                                      : make_float4(0.f, 0.f, 0.f, 0.f);
            int addr = swz_base(row, q >> 1) + (q & 1) * 4;
            unsigned short* p = &lA[addr];
            p[0] = f2bf(v.x); p[1] = f2bf(v.y); p[2] = f2bf(v.z); p[3] = f2bf(v.w);
        }
    }
    // ---- stage Wa^T ----
    {
        const int4* Wsrc = (const int4*)WaT;    // 16B = one 8-elem chunk
        #pragma unroll
        for (int i = 0; i < 8; ++i) {
            int c = tid + 256 * i;              // 0..2047
            int row = c >> 4, q = c & 15;       // q: chunk index
            *(int4*)&lW[swz_base(row, q)] = Wsrc[c];
        }
    }
    __syncthreads();

    const int am = lane & 15;
    const int kq = (lane >> 4) * 8;             // quad k offset

    f32x4 acc[4][4];
    #pragma unroll
    for (int i = 0; i < 4; ++i)
        #pragma unroll
        for (int j = 0; j < 4; ++j) acc[i][j] = (f32x4){0.f, 0.f, 0.f, 0.f};

    // ---- matmul 1: T = A @ Wa ----
    #pragma unroll
    for (int ks = 0; ks < 4; ++ks) {
        int k0 = ks * 32 + kq;
        bf16x8 af[4], bq[4];
        #pragma unroll
        for (int i = 0; i < 4; ++i)
            af[i] = *(const bf16x8*)&lA[swz_base(wr + i * 16 + am, k0 >> 3)];
        #pragma unroll
        for (int j = 0; j < 4; ++j)
            bq[j] = *(const bf16x8*)&lW[swz_base(wc + j * 16 + am, k0 >> 3)];
        #pragma unroll
        for (int i = 0; i < 4; ++i)
            #pragma unroll
            for (int j = 0; j < 4; ++j)
                acc[i][j] = __builtin_amdgcn_mfma_f32_16x16x32_bf16(af[i], bq[j], acc[i][j], 0, 0, 0);
    }
    __syncthreads();   // all lA/lW reads complete

    // ---- T = relu(acc + ba) -> lA (bf16); restage lW = Wb^T ----
    #pragma unroll
    for (int j = 0; j < 4; ++j) {
        int col = wc + j * 16 + am;
        float bias = ba[col];
        #pragma unroll
        for (int i = 0; i < 4; ++i) {
            int rowb = wr + i * 16 + (lane >> 4) * 4;
            #pragma unroll
            for (int r = 0; r < 4; ++r) {
                float t = acc[i][j][r] + bias;
                t = t > 0.f ? t : 0.f;
                int row = rowb + r;
                lA[swz_base(row, col >> 3) + (col & 7)] = f2bf(t);
            }
        }
    }
    {
        const int4* Wsrc = (const int4*)WbT;
        #pragma unroll
        for (int i = 0; i < 8; ++i) {
            int c = tid + 256 * i;
            int row = c >> 4, q = c & 15;
            *(int4*)&lW[swz_base(row, q)] = Wsrc[c];
        }
    }
    __syncthreads();

    // ---- matmul 2: R = T @ Wb ----
    #pragma unroll
    for (int i = 0; i < 4; ++i)
        #pragma unroll
        for (int j = 0; j < 4; ++j) acc[i][j] = (f32x4){0.f, 0.f, 0.f, 0.f};

    #pragma unroll
    for (int ks = 0; ks < 4; ++ks) {
        int k0 = ks * 32 + kq;
        bf16x8 af[4], bq[4];
        #pragma unroll
        for (int i = 0; i < 4; ++i)
            af[i] = *(const bf16x8*)&lA[swz_base(wr + i * 16 + am, k0 >> 3)];
        #pragma unroll
        for (int j = 0; j < 4; ++j)
            bq[j] = *(const bf16x8*)&lW[swz_base(wc + j * 16 + am, k0 >> 3)];
        #pragma unroll
        for (int i = 0; i < 4; ++i)
            #pragma unroll
            for (int j = 0; j < 4; ++j)
                acc[i][j] = __builtin_amdgcn_mfma_f32_16x16x32_bf16(af[i], bq[j], acc[i][j], 0, 0, 0);
    }

    // ---- epilogue: Y = relu(acc + bb), fp32 ----
    #pragma unroll
    for (int j = 0; j < 4; ++j) {
        int col = wc + j * 16 + am;
        float bias = bb[col];
        #pragma unroll
        for (int i = 0; i < 4; ++i) {
            int rowb = wr + i * 16 + (lane >> 4) * 4;
            #pragma unroll
            for (int r = 0; r < 4; ++r) {
                int row = r0 + rowb + r;
                if (row < N) {
                    float t = acc[i][j][r] + bias;
                    Y[(size_t)row * 128 + col] = t > 0.f ? t : 0.f;
                }
            }
        }
    }
}

// ---------------- pooling: g[batch[n]] += h[n], batch sorted ----------------
#define PSTRIP 8
__global__ void k_pool(const float* __restrict__ H, const int* __restrict__ batch,
                       int N, float* __restrict__ G) {
    int wid = (blockIdx.x * blockDim.x + threadIdx.x) >> 6;
    int lane = threadIdx.x & 63;
    int n0 = wid * PSTRIP;
    if (n0 >= N) return;
    int n1 = n0 + PSTRIP; if (n1 > N) n1 = N;
    const size_t fo = (size_t)lane * 2;
    int cur = batch[n0];
    float2 acc = {0.f, 0.f};
    for (int n = n0; n < n1; ++n) {
        int b = batch[n];
        if (b != cur) {
            atomicAdd(&G[(size_t)cur * 128 + fo], acc.x);
            atomicAdd(&G[(size_t)cur * 128 + fo + 1], acc.y);
            acc.x = 0.f; acc.y = 0.f;
            cur = b;
        }
        float2 v = *(const float2*)&H[(size_t)n * 128 + fo];
        acc.x += v.x; acc.y += v.y;
    }
    atomicAdd(&G[(size_t)cur * 128 + fo], acc.x);
    atomicAdd(&G[(size_t)cur * 128 + fo + 1], acc.y);
}

// ---------------- head: out = log_softmax(relu(g@Wl1+bl1)@Wl2+bl2) ----------------
__global__ void k_head(const float* __restrict__ G,
                       const float* __restrict__ Wl1, const float* __restrict__ bl1,
                       const float* __restrict__ Wl2, const float* __restrict__ bl2,
                       int C, float* __restrict__ out) {
    __shared__ float sg[128];
    __shared__ float sh[128];
    __shared__ float sl[16];
    int row = blockIdx.x;
    int t = threadIdx.x;
    sg[t] = G[(size_t)row * 128 + t];
    __syncthreads();
    float a = bl1[t];
    for (int k = 0; k < 128; ++k) a += sg[k] * Wl1[k * 128 + t];
    sh[t] = a > 0.f ? a : 0.f;
    __syncthreads();
    if (t < C) {
        float l = bl2[t];
        for (int k = 0; k < 128; ++k) l += sh[k] * Wl2[k * C + t];
        sl[t] = l;
    }
    __syncthreads();
    if (t < C) {
        float m = -1e30f;
        for (int j = 0; j < C; ++j) m = fmaxf(m, sl[j]);
        float s = 0.f;
        for (int j = 0; j < C; ++j) s += __expf(sl[j] - m);
        out[(size_t)row * C + t] = sl[t] - m - __logf(s);
    }
}

extern "C" void kernel_launch(void* const* d_in, const int* in_sizes, int n_in,
                              void* d_out, int out_size, void* d_ws, size_t ws_size,
                              hipStream_t stream) {
    const float* x    = (const float*)d_in[0];
    const int*   ei   = (const int*)d_in[1];     // [2][E], int32 per harness convention
    const int*   batch= (const int*)d_in[2];
    const float* W1a  = (const float*)d_in[3];
    const float* b1a  = (const float*)d_in[4];
    const float* W1b  = (const float*)d_in[5];
    const float* b1b  = (const float*)d_in[6];
    const float* W2a  = (const float*)d_in[7];
    const float* b2a  = (const float*)d_in[8];
    const float* W2b  = (const float*)d_in[9];
    const float* b2b  = (const float*)d_in[10];
    const float* Wl1  = (const float*)d_in[11];
    const float* bl1  = (const float*)d_in[12];
    const float* Wl2  = (const float*)d_in[13];
    const float* bl2  = (const float*)d_in[14];
    float* out = (float*)d_out;

    const int N = in_sizes[2];
    const int E = in_sizes[1] / 2;
    const int C = in_sizes[13] / 128;

    char* p = (char*)d_ws;
    auto alloc = [&](size_t bytes) {
        char* r = p;
        p += (bytes + 255) & ~(size_t)255;
        return r;
    };
    float* hA  = (float*)alloc((size_t)N * 128 * 4);
    float* hB  = (float*)alloc((size_t)N * 128 * 4);
    float* g   = (float*)alloc((size_t)NUM_GRAPHS * 128 * 4);
    int* deg   = (int*)alloc((size_t)N * 4);
    int* excl  = (int*)alloc((size_t)N * 4);
    int* rp    = (int*)alloc((size_t)(N + 1) * 4);
    int* cursor= (int*)alloc((size_t)N * 4);
    int* bsum  = (int*)alloc(4096);
    int* srcs  = (int*)alloc((size_t)E * 4);
    unsigned short* wt = (unsigned short*)alloc((size_t)4 * 16384 * 2);
    (void)ws_size; (void)n_in; (void)out_size;

    const int nb = (N + 255) / 256;
    const int eb = (E + 255) / 256;

    hipMemsetAsync(deg, 0, (size_t)N * 4, stream);
    hipMemsetAsync(g, 0, (size_t)NUM_GRAPHS * 128 * 4, stream);

    // CSR build (edge_index is reused by both conv layers)
    k_deg<<<eb, 256, 0, stream>>>(ei + E, E, deg);
    k_scan1<<<nb, 256, 0, stream>>>(deg, N, excl, bsum);
    k_scan2<<<1, 1024, 0, stream>>>(bsum, nb);
    k_scan3<<<nb, 256, 0, stream>>>(excl, bsum, N, E, rp, cursor);
    k_fill<<<eb, 256, 0, stream>>>(ei, E, cursor, srcs);

    // bf16-transposed weights for the two conv MLPs
    k_prepw<<<64, 256, 0, stream>>>(W1a, wt);
    k_prepw<<<64, 256, 0, stream>>>(W1b, wt + 16384);
    k_prepw<<<64, 256, 0, stream>>>(W2a, wt + 2 * 16384);
    k_prepw<<<64, 256, 0, stream>>>(W2b, wt + 3 * 16384);

    const int ab = (N + 3) / 4;      // 4 waves per block, 1 node per wave
    const int mb = (N + 127) / 128;

    // conv1
    k_agg<<<ab, 256, 0, stream>>>(x, rp, srcs, N, hA);
    k_mlp<<<mb, 256, 0, stream>>>(hA, N, wt, b1a, wt + 16384, b1b, hB);
    // conv2
    k_agg<<<ab, 256, 0, stream>>>(hB, rp, srcs, N, hA);
    k_mlp<<<mb, 256, 0, stream>>>(hA, N, wt + 2 * 16384, b2a, wt + 3 * 16384, b2b, hB);

    // pool + head
    const int pw = (N + PSTRIP - 1) / PSTRIP;
    const int pb = (pw + 3) / 4;
    k_pool<<<pb, 256, 0, stream>>>(hB, batch, N, g);
    k_head<<<NUM_GRAPHS, 128, 0, stream>>>(g, Wl1, bl1, Wl2, bl2, C, out);
}

// Round 2
// 468.805 us; speedup vs baseline: 1.4231x; 1.4231x over previous
//
#include <hip/hip_runtime.h>
#include <hip/hip_bf16.h>
#include <math.h>

#define NUM_GRAPHS 1024

typedef __attribute__((ext_vector_type(8))) short bf16x8;
typedef __attribute__((ext_vector_type(4))) float f32x4;

static __device__ __forceinline__ unsigned short f2bf(float f) {
    union { float f; unsigned u; } v; v.f = f;
    unsigned r = v.u + 0x7fffu + ((v.u >> 16) & 1u);   // round-to-nearest-even
    return (unsigned short)(r >> 16);
}

// ---------------- CSR build ----------------
// deg histogram + per-edge rank (arrival order within its dst) in ONE pass.
// rank makes the fill atomic-free: slot = rp[d] + rank[e].
__global__ void k_degrank(const int* __restrict__ dstI, int E,
                          int* __restrict__ deg, int* __restrict__ rank) {
    int e = blockIdx.x * 256 + threadIdx.x;
    if (e < E) rank[e] = atomicAdd(&deg[dstI[e]], 1);
}

__global__ void k_scan1(const int* __restrict__ deg, int N,
                        int* __restrict__ excl, int* __restrict__ bsum) {
    __shared__ int s[256];
    int i = blockIdx.x * 256 + threadIdx.x;
    int v = (i < N) ? deg[i] : 0;
    s[threadIdx.x] = v;
    __syncthreads();
    for (int off = 1; off < 256; off <<= 1) {
        int t = (threadIdx.x >= off) ? s[threadIdx.x - off] : 0;
        __syncthreads();
        s[threadIdx.x] += t;
        __syncthreads();
    }
    if (i < N) excl[i] = s[threadIdx.x] - v;
    if (threadIdx.x == 255) bsum[blockIdx.x] = s[255];
}

__global__ void k_scan2(int* __restrict__ bsum, int nb) {
    __shared__ int s[1024];
    int t = threadIdx.x;
    int v = (t < nb) ? bsum[t] : 0;
    s[t] = v;
    __syncthreads();
    for (int off = 1; off < 1024; off <<= 1) {
        int u = (t >= off) ? s[t - off] : 0;
        __syncthreads();
        s[t] += u;
        __syncthreads();
    }
    if (t < nb) bsum[t] = s[t] - v;   // exclusive block offsets
}

__global__ void k_scan3(const int* __restrict__ excl, const int* __restrict__ bsum,
                        int N, int E, int* __restrict__ rp) {
    int i = blockIdx.x * 256 + threadIdx.x;
    if (i < N) rp[i] = excl[i] + bsum[i >> 8];
    if (i == 0) rp[N] = E;
}

// Atomic-free fill, 3 temporal passes over dst ranges so each pass's srcs
// window (~2.1 MB) stays L2-resident -> write-backs merge instead of
// ping-ponging 64B lines to HBM.
#define FILL_PASSES 3
#define FILL_RANGE 33334
__global__ void k_fill3(const int* __restrict__ ei, const int* __restrict__ rank,
                        int E, const int* __restrict__ rp, int* __restrict__ srcs) {
    const int tid0 = blockIdx.x * 256 + threadIdx.x;
    const int stride = gridDim.x * 256;
    for (int pass = 0; pass < FILL_PASSES; ++pass) {
        const int lo = pass * FILL_RANGE;
        const int hi = lo + FILL_RANGE;
        for (int e = tid0; e < E; e += stride) {
            int d = ei[(size_t)E + e];
            if (d >= lo && d < hi) {
                srcs[rp[d] + rank[e]] = ei[e];
            }
        }
    }
}

// ---------------- x -> bf16 (packed pairs in uint) ----------------
__global__ void k_x2bf(const float* __restrict__ x, int n4, unsigned* __restrict__ xb) {
    // n4 = N*128/4 ; thread handles 4 floats -> 2 uints
    int i = blockIdx.x * 256 + threadIdx.x;
    int stride = gridDim.x * 256;
    const float4* x4 = (const float4*)x;
    for (; i < n4; i += stride) {
        float4 v = x4[i];
        unsigned lo = (unsigned)f2bf(v.x) | ((unsigned)f2bf(v.y) << 16);
        unsigned hi = (unsigned)f2bf(v.z) | ((unsigned)f2bf(v.w) << 16);
        ((uint2*)xb)[i] = make_uint2(lo, hi);
    }
}

// ---------------- aggregation (bf16 in / bf16 out, fp32 accumulate) ----------------
// out[n] = H[n] + sum_{e: dst=n} H[src_e]; one wave per node; lane holds 1 uint
// = 2 bf16 features (cols 2*lane, 2*lane+1); row = 64 uints = 256 B.
__global__ void k_aggb(const unsigned* __restrict__ H, const int* __restrict__ rp,
                       const int* __restrict__ srcs, int N, unsigned* __restrict__ out) {
    int wid = (blockIdx.x * blockDim.x + threadIdx.x) >> 6;
    int lane = threadIdx.x & 63;
    if (wid >= N) return;
    int beg = rp[wid], end = rp[wid + 1];
    unsigned u0 = H[(size_t)wid * 64 + lane];
    float accL = __uint_as_float(u0 << 16);
    float accH = __uint_as_float(u0 & 0xffff0000u);
    int j = beg;
    for (; j + 4 <= end; j += 4) {
        int s0 = srcs[j], s1 = srcs[j + 1], s2 = srcs[j + 2], s3 = srcs[j + 3];
        unsigned v0 = H[(size_t)s0 * 64 + lane];
        unsigned v1 = H[(size_t)s1 * 64 + lane];
        unsigned v2 = H[(size_t)s2 * 64 + lane];
        unsigned v3 = H[(size_t)s3 * 64 + lane];
        accL += __uint_as_float(v0 << 16) + __uint_as_float(v1 << 16)
              + __uint_as_float(v2 << 16) + __uint_as_float(v3 << 16);
        accH += __uint_as_float(v0 & 0xffff0000u) + __uint_as_float(v1 & 0xffff0000u)
              + __uint_as_float(v2 & 0xffff0000u) + __uint_as_float(v3 & 0xffff0000u);
    }
    for (; j < end; ++j) {
        unsigned v = H[(size_t)srcs[j] * 64 + lane];
        accL += __uint_as_float(v << 16);
        accH += __uint_as_float(v & 0xffff0000u);
    }
    out[(size_t)wid * 64 + lane] = (unsigned)f2bf(accL) | ((unsigned)f2bf(accH) << 16);
}

// ---------------- weight prep: fp32 W[k][n] -> bf16 W^T[n][k] ----------------
__global__ void k_prepw(const float* __restrict__ W, unsigned short* __restrict__ WT) {
    int idx = blockIdx.x * 256 + threadIdx.x;   // 0..16383
    int k = idx >> 7, n = idx & 127;
    WT[n * 128 + k] = f2bf(W[idx]);
}

// ---------------- fused 2-layer MLP (bf16 in/out): Y = relu(relu(U@Wa+ba)@Wb+bb) ----------------
// XOR-chunk swizzle: logical (row, chunk of 8 elems) -> row*128 + ((chunk ^ (row&7))*8
__device__ __forceinline__ int swz_base(int row, int chunk) {
    return row * 128 + ((chunk ^ (row & 7)) << 3);
}

__global__ __launch_bounds__(256, 2)
void k_mlp(const unsigned short* __restrict__ U, int N,
           const unsigned short* __restrict__ WaT, const float* __restrict__ ba,
           const unsigned short* __restrict__ WbT, const float* __restrict__ bb,
           unsigned short* __restrict__ Y) {
    __shared__ unsigned short lA[128 * 128];   // 32 KB: A tile, then T tile
    __shared__ unsigned short lW[128 * 128];   // 32 KB: Wa^T, then Wb^T

    const int tid = threadIdx.x;
    const int lane = tid & 63;
    const int w = tid >> 6;              // wave 0..3
    const int wr = (w >> 1) * 64;        // wave row offset
    const int wc = (w & 1) * 64;         // wave col offset
    const int r0 = blockIdx.x * 128;

    // ---- stage A: bf16 global -> LDS (swizzled), 16B = one 8-elem chunk ----
    {
        const uint4* U4 = (const uint4*)U;
        #pragma unroll
        for (int i = 0; i < 8; ++i) {
            int c = tid + 256 * i;              // 0..2047
            int row = c >> 4, q = c & 15;
            uint4 v = (r0 + row < N) ? U4[(size_t)(r0 + row) * 16 + q]
                                     : make_uint4(0u, 0u, 0u, 0u);
            *(uint4*)&lA[swz_base(row, q)] = v;
        }
    }
    // ---- stage Wa^T ----
    {
        const uint4* Wsrc = (const uint4*)WaT;
        #pragma unroll
        for (int i = 0; i < 8; ++i) {
            int c = tid + 256 * i;
            int row = c >> 4, q = c & 15;
            *(uint4*)&lW[swz_base(row, q)] = Wsrc[c];
        }
    }
    __syncthreads();

    const int am = lane & 15;
    const int kq = (lane >> 4) * 8;             // quad k offset

    f32x4 acc[4][4];
    #pragma unroll
    for (int i = 0; i < 4; ++i)
        #pragma unroll
        for (int j = 0; j < 4; ++j) acc[i][j] = (f32x4){0.f, 0.f, 0.f, 0.f};

    // ---- matmul 1: T = A @ Wa ----
    #pragma unroll
    for (int ks = 0; ks < 4; ++ks) {
        int k0 = ks * 32 + kq;
        bf16x8 af[4], bq[4];
        #pragma unroll
        for (int i = 0; i < 4; ++i)
            af[i] = *(const bf16x8*)&lA[swz_base(wr + i * 16 + am, k0 >> 3)];
        #pragma unroll
        for (int j = 0; j < 4; ++j)
            bq[j] = *(const bf16x8*)&lW[swz_base(wc + j * 16 + am, k0 >> 3)];
        #pragma unroll
        for (int i = 0; i < 4; ++i)
            #pragma unroll
            for (int j = 0; j < 4; ++j)
                acc[i][j] = __builtin_amdgcn_mfma_f32_16x16x32_bf16(af[i], bq[j], acc[i][j], 0, 0, 0);
    }
    __syncthreads();   // all lA/lW reads complete

    // ---- T = relu(acc + ba) -> lA (bf16); restage lW = Wb^T ----
    #pragma unroll
    for (int j = 0; j < 4; ++j) {
        int col = wc + j * 16 + am;
        float bias = ba[col];
        #pragma unroll
        for (int i = 0; i < 4; ++i) {
            int rowb = wr + i * 16 + (lane >> 4) * 4;
            #pragma unroll
            for (int r = 0; r < 4; ++r) {
                float t = acc[i][j][r] + bias;
                t = t > 0.f ? t : 0.f;
                int row = rowb + r;
                lA[swz_base(row, col >> 3) + (col & 7)] = f2bf(t);
            }
        }
    }
    {
        const uint4* Wsrc = (const uint4*)WbT;
        #pragma unroll
        for (int i = 0; i < 8; ++i) {
            int c = tid + 256 * i;
            int row = c >> 4, q = c & 15;
            *(uint4*)&lW[swz_base(row, q)] = Wsrc[c];
        }
    }
    __syncthreads();

    // ---- matmul 2: R = T @ Wb ----
    #pragma unroll
    for (int i = 0; i < 4; ++i)
        #pragma unroll
        for (int j = 0; j < 4; ++j) acc[i][j] = (f32x4){0.f, 0.f, 0.f, 0.f};

    #pragma unroll
    for (int ks = 0; ks < 4; ++ks) {
        int k0 = ks * 32 + kq;
        bf16x8 af[4], bq[4];
        #pragma unroll
        for (int i = 0; i < 4; ++i)
            af[i] = *(const bf16x8*)&lA[swz_base(wr + i * 16 + am, k0 >> 3)];
        #pragma unroll
        for (int j = 0; j < 4; ++j)
            bq[j] = *(const bf16x8*)&lW[swz_base(wc + j * 16 + am, k0 >> 3)];
        #pragma unroll
        for (int i = 0; i < 4; ++i)
            #pragma unroll
            for (int j = 0; j < 4; ++j)
                acc[i][j] = __builtin_amdgcn_mfma_f32_16x16x32_bf16(af[i], bq[j], acc[i][j], 0, 0, 0);
    }

    // ---- epilogue: Y = relu(acc + bb), bf16 ----
    #pragma unroll
    for (int j = 0; j < 4; ++j) {
        int col = wc + j * 16 + am;
        float bias = bb[col];
        #pragma unroll
        for (int i = 0; i < 4; ++i) {
            int rowb = wr + i * 16 + (lane >> 4) * 4;
            #pragma unroll
            for (int r = 0; r < 4; ++r) {
                int row = r0 + rowb + r;
                if (row < N) {
                    float t = acc[i][j][r] + bias;
                    t = t > 0.f ? t : 0.f;
                    Y[(size_t)row * 128 + col] = f2bf(t);
                }
            }
        }
    }
}

// ---------------- pooling: g[batch[n]] += h[n] (bf16 in, fp32 atomic out) ----------------
#define PSTRIP 8
__global__ void k_pool(const unsigned* __restrict__ H, const int* __restrict__ batch,
                       int N, float* __restrict__ G) {
    int wid = (blockIdx.x * blockDim.x + threadIdx.x) >> 6;
    int lane = threadIdx.x & 63;
    int n0 = wid * PSTRIP;
    if (n0 >= N) return;
    int n1 = n0 + PSTRIP; if (n1 > N) n1 = N;
    const size_t fo = (size_t)lane * 2;
    int cur = batch[n0];
    float aL = 0.f, aH = 0.f;
    for (int n = n0; n < n1; ++n) {
        int b = batch[n];
        if (b != cur) {
            atomicAdd(&G[(size_t)cur * 128 + fo], aL);
            atomicAdd(&G[(size_t)cur * 128 + fo + 1], aH);
            aL = 0.f; aH = 0.f;
            cur = b;
        }
        unsigned v = H[(size_t)n * 64 + lane];
        aL += __uint_as_float(v << 16);
        aH += __uint_as_float(v & 0xffff0000u);
    }
    atomicAdd(&G[(size_t)cur * 128 + fo], aL);
    atomicAdd(&G[(size_t)cur * 128 + fo + 1], aH);
}

// ---------------- head: out = log_softmax(relu(g@Wl1+bl1)@Wl2+bl2) ----------------
__global__ void k_head(const float* __restrict__ G,
                       const float* __restrict__ Wl1, const float* __restrict__ bl1,
                       const float* __restrict__ Wl2, const float* __restrict__ bl2,
                       int C, float* __restrict__ out) {
    __shared__ float sg[128];
    __shared__ float sh[128];
    __shared__ float sl[16];
    int row = blockIdx.x;
    int t = threadIdx.x;
    sg[t] = G[(size_t)row * 128 + t];
    __syncthreads();
    float a = bl1[t];
    for (int k = 0; k < 128; ++k) a += sg[k] * Wl1[k * 128 + t];
    sh[t] = a > 0.f ? a : 0.f;
    __syncthreads();
    if (t < C) {
        float l = bl2[t];
        for (int k = 0; k < 128; ++k) l += sh[k] * Wl2[k * C + t];
        sl[t] = l;
    }
    __syncthreads();
    if (t < C) {
        float m = -1e30f;
        for (int j = 0; j < C; ++j) m = fmaxf(m, sl[j]);
        float s = 0.f;
        for (int j = 0; j < C; ++j) s += __expf(sl[j] - m);
        out[(size_t)row * C + t] = sl[t] - m - __logf(s);
    }
}

extern "C" void kernel_launch(void* const* d_in, const int* in_sizes, int n_in,
                              void* d_out, int out_size, void* d_ws, size_t ws_size,
                              hipStream_t stream) {
    const float* x    = (const float*)d_in[0];
    const int*   ei   = (const int*)d_in[1];     // [2][E]
    const int*   batch= (const int*)d_in[2];
    const float* W1a  = (const float*)d_in[3];
    const float* b1a  = (const float*)d_in[4];
    const float* W1b  = (const float*)d_in[5];
    const float* b1b  = (const float*)d_in[6];
    const float* W2a  = (const float*)d_in[7];
    const float* b2a  = (const float*)d_in[8];
    const float* W2b  = (const float*)d_in[9];
    const float* b2b  = (const float*)d_in[10];
    const float* Wl1  = (const float*)d_in[11];
    const float* bl1  = (const float*)d_in[12];
    const float* Wl2  = (const float*)d_in[13];
    const float* bl2  = (const float*)d_in[14];
    float* out = (float*)d_out;

    const int N = in_sizes[2];
    const int E = in_sizes[1] / 2;
    const int C = in_sizes[13] / 128;

    char* p = (char*)d_ws;
    auto alloc = [&](size_t bytes) {
        char* r = p;
        p += (bytes + 255) & ~(size_t)255;
        return r;
    };
    unsigned* xb = (unsigned*)alloc((size_t)N * 64 * 4);          // x in bf16
    unsigned* hA = (unsigned*)alloc((size_t)N * 64 * 4);          // agg output (bf16)
    unsigned* hB = (unsigned*)alloc((size_t)N * 64 * 4);          // conv output (bf16)
    float* g   = (float*)alloc((size_t)NUM_GRAPHS * 128 * 4);
    int* deg   = (int*)alloc((size_t)N * 4);
    int* excl  = (int*)alloc((size_t)N * 4);
    int* rp    = (int*)alloc((size_t)(N + 1) * 4);
    int* rank  = (int*)alloc((size_t)E * 4);
    int* bsum  = (int*)alloc(4096);
    int* srcs  = (int*)alloc((size_t)E * 4);
    unsigned short* wt = (unsigned short*)alloc((size_t)4 * 16384 * 2);
    (void)ws_size; (void)n_in; (void)out_size;

    const int nb = (N + 255) / 256;
    const int eb = (E + 255) / 256;

    hipMemsetAsync(deg, 0, (size_t)N * 4, stream);
    hipMemsetAsync(g, 0, (size_t)NUM_GRAPHS * 128 * 4, stream);

    // CSR build (atomic-free fill via per-edge rank)
    k_degrank<<<eb, 256, 0, stream>>>(ei + E, E, deg, rank);
    k_scan1<<<nb, 256, 0, stream>>>(deg, N, excl, bsum);
    k_scan2<<<1, 1024, 0, stream>>>(bsum, nb);
    k_scan3<<<nb, 256, 0, stream>>>(excl, bsum, N, E, rp);
    k_fill3<<<2048, 256, 0, stream>>>(ei, rank, E, rp, srcs);

    // bf16 weights + bf16 x
    k_prepw<<<64, 256, 0, stream>>>(W1a, wt);
    k_prepw<<<64, 256, 0, stream>>>(W1b, wt + 16384);
    k_prepw<<<64, 256, 0, stream>>>(W2a, wt + 2 * 16384);
    k_prepw<<<64, 256, 0, stream>>>(W2b, wt + 3 * 16384);
    k_x2bf<<<4096, 256, 0, stream>>>(x, N * 32, xb);

    const int ab = (N + 3) / 4;      // 4 waves per block, 1 node per wave
    const int mb = (N + 127) / 128;

    // conv1
    k_aggb<<<ab, 256, 0, stream>>>(xb, rp, srcs, N, hA);
    k_mlp<<<mb, 256, 0, stream>>>((const unsigned short*)hA, N, wt, b1a, wt + 16384, b1b,
                                  (unsigned short*)hB);
    // conv2
    k_aggb<<<ab, 256, 0, stream>>>(hB, rp, srcs, N, hA);
    k_mlp<<<mb, 256, 0, stream>>>((const unsigned short*)hA, N, wt + 2 * 16384, b2a,
                                  wt + 3 * 16384, b2b, (unsigned short*)hB);

    // pool + head
    const int pw = (N + PSTRIP - 1) / PSTRIP;
    const int pb = (pw + 3) / 4;
    k_pool<<<pb, 256, 0, stream>>>(hB, batch, N, g);
    k_head<<<NUM_GRAPHS, 128, 0, stream>>>(g, Wl1, bl1, Wl2, bl2, C, out);
}